// Round 5
// baseline (189.218 us; speedup 1.0000x reference)
//
#include <hip/hip_runtime.h>
#include <stdint.h>

#define NROWS 8192
#define MCOLS 8192
#define DDIM  64

typedef _Float16 half8   __attribute__((ext_vector_type(8)));
typedef float    floatx4 __attribute__((ext_vector_type(4)));

// ---------- monotone float <-> uint key (for atomicMax argmax) ----------
__device__ __forceinline__ unsigned f2key(float f) {
  unsigned u = __float_as_uint(f);
  return (u & 0x80000000u) ? ~u : (u | 0x80000000u);
}
__device__ __forceinline__ float key2f(unsigned k) {
  unsigned u = (k & 0x80000000u) ? (k & 0x7fffffffu) : ~k;
  return __uint_as_float(u);
}

// ---------- fused: fp16-split conversion + row norms + accumulator init -------
// Packs fp32 -> (fp16 hi, fp16 lo*2^11) in 16x16x32 MFMA fragment-lane order:
// unit t = (panel*2 + c)*64 + lane holds row = panel*16+(lane&15),
// k = c*32 + (lane>>4)*8 + j, j in [0,8).  Also computes row squared-norms
// and zeroes the global reduction accumulators + the completion counter.
__global__ void convert_kernel(const float* __restrict__ x, const float* __restrict__ y,
                               _Float16* __restrict__ xh, _Float16* __restrict__ xl,
                               _Float16* __restrict__ yh, _Float16* __restrict__ yl,
                               float* __restrict__ xn, float* __restrict__ yn,
                               unsigned long long* __restrict__ rk,
                               unsigned long long* __restrict__ ck,
                               float* __restrict__ rs, float* __restrict__ cs,
                               unsigned* __restrict__ done) {
  __shared__ float lnorm[32];
  const int gid = blockIdx.x * 256 + threadIdx.x;      // 0 .. 131071
  if (gid < 8192) { rk[gid] = 0ull; rs[gid] = 0.0f; ck[gid] = 0ull; cs[gid] = 0.0f; }
  if (gid == 0) *done = 0u;
  if (threadIdx.x < 32) lnorm[threadIdx.x] = 0.0f;
  __syncthreads();

  const float* src; _Float16 *dh, *dl; float* nout; int t, rowbase;
  if (gid < 65536) { src = x; dh = xh; dl = xl; nout = xn; t = gid;
                     rowbase = blockIdx.x * 32; }
  else             { src = y; dh = yh; dl = yl; nout = yn; t = gid - 65536;
                     rowbase = (blockIdx.x - 256) * 32; }

  const int lane = t & 63;
  const int c    = (t >> 6) & 1;
  const int p    = t >> 7;
  const int row  = p * 16 + (lane & 15);
  const int k0   = c * 32 + ((lane >> 4) << 3);
  const float* s = src + (size_t)row * DDIM + k0;

  _Float16 hbuf[8], lbuf[8];
  float s8 = 0.0f;
  #pragma unroll
  for (int j = 0; j < 8; ++j) {
    float f = s[j];
    _Float16 h = (_Float16)f;
    hbuf[j] = h;
    lbuf[j] = (_Float16)((f - (float)h) * 2048.0f);
    s8 = fmaf(f, f, s8);
  }
  size_t o = (size_t)t * 8;
  *(half8*)(dh + o) = *(half8*)hbuf;
  *(half8*)(dl + o) = *(half8*)lbuf;

  atomicAdd(&lnorm[((p & 1) << 4) | (t & 15)], s8);
  __syncthreads();
  if (threadIdx.x < 32) nout[rowbase + threadIdx.x] = lnorm[threadIdx.x];
}

// ---------- main pass: block = 4 waves, 128 rows x 512 cols; fused finalize ---
__global__ __launch_bounds__(256, 4) void mfma_tile_kernel(
    const _Float16* __restrict__ xh, const _Float16* __restrict__ xl,
    const _Float16* __restrict__ yh, const _Float16* __restrict__ yl,
    const float* __restrict__ xn, const float* __restrict__ yn,
    unsigned long long* __restrict__ row_key, float* __restrict__ row_sum,
    unsigned long long* __restrict__ col_key, float* __restrict__ col_sum,
    unsigned* __restrict__ done, float* __restrict__ out)
{
  __shared__ unsigned long long lkey[512];   // per-block col keys (4 KB)
  __shared__ float              lsum[512];   //                    (2 KB)
  __shared__ unsigned           lastflag;

  const int wave = threadIdx.x >> 6;
  const int lane = threadIdx.x & 63;
  const int l15  = lane & 15;
  const int g    = lane >> 4;                // row-group 0..3
  const int ap0  = blockIdx.y * 8 + wave * 2;       // first of 2 A panels
  const int ro   = ap0 * 16 + g * 4;                // first row this lane covers
  const int colbase = blockIdx.x * 512;

  lkey[threadIdx.x]       = 0ull;
  lkey[threadIdx.x + 256] = 0ull;
  lsum[threadIdx.x]       = 0.0f;
  lsum[threadIdx.x + 256] = 0.0f;
  __syncthreads();

  // ---- A fragments: 2 panels x (2 hi + 2 lo chunks), 32 VGPRs ----
  const half8* xh8 = (const half8*)xh;
  const half8* xl8 = (const half8*)xl;
  const half8* yh8 = (const half8*)yh;
  const half8* yl8 = (const half8*)yl;
  const size_t a0 = (size_t)ap0 * 128 + lane;
  half8 Ah[2][2], Al[2][2];
  #pragma unroll
  for (int p = 0; p < 2; ++p) {
    Ah[p][0] = xh8[a0 + p * 128];      Ah[p][1] = xh8[a0 + p * 128 + 64];
    Al[p][0] = xl8[a0 + p * 128];      Al[p][1] = xl8[a0 + p * 128 + 64];
  }

  // ---- per-row state: 8 rows/lane ----
  float xne[8], rsum[8], rmax[8]; int ridx[8];
  #pragma unroll
  for (int s = 0; s < 8; ++s) {
    xne[s]  = xn[ro + ((s >> 2) << 4) + (s & 3)];
    rsum[s] = 0.0f; rmax[s] = -3.4e38f; ridx[s] = 0;
  }

  // ---- jt loop over 32 col panels, B prefetched one panel ahead ----
  const size_t bbase = (size_t)(blockIdx.x * 32) * 128 + lane;
  half8 nbh0 = yh8[bbase], nbh1 = yh8[bbase + 64];
  half8 nbl0 = yl8[bbase], nbl1 = yl8[bbase + 64];

  for (int jt = 0; jt < 32; ++jt) {
    const half8 bh0 = nbh0, bh1 = nbh1, bl0 = nbl0, bl1 = nbl1;
    const int col = colbase + jt * 16 + l15;
    const float ync = yn[col];
    if (jt < 31) {
      const size_t nb = bbase + (size_t)(jt + 1) * 128;
      nbh0 = yh8[nb];  nbh1 = yh8[nb + 64];
      nbl0 = yl8[nb];  nbl1 = yl8[nb + 64];
    }

    float csum = 0.0f, cmax = -3.4e38f; int cs8 = 0;
    #pragma unroll
    for (int p = 0; p < 2; ++p) {
      floatx4 c1 = {}, c2 = {};
      c1 = __builtin_amdgcn_mfma_f32_16x16x32_f16(Ah[p][0], bh0, c1, 0, 0, 0);
      c1 = __builtin_amdgcn_mfma_f32_16x16x32_f16(Ah[p][1], bh1, c1, 0, 0, 0);
      c2 = __builtin_amdgcn_mfma_f32_16x16x32_f16(Al[p][0], bh0, c2, 0, 0, 0);
      c2 = __builtin_amdgcn_mfma_f32_16x16x32_f16(Al[p][1], bh1, c2, 0, 0, 0);
      c2 = __builtin_amdgcn_mfma_f32_16x16x32_f16(Ah[p][0], bl0, c2, 0, 0, 0);
      c2 = __builtin_amdgcn_mfma_f32_16x16x32_f16(Ah[p][1], bl1, c2, 0, 0, 0);
      #pragma unroll
      for (int r = 0; r < 4; ++r) {
        const int s = p * 4 + r;
        float dot = fmaf(c2[r], (1.0f / 2048.0f), c1[r]);
        float sq  = fmaxf(fmaf(-2.0f, dot, xne[s] + ync), 0.0f);
        float d   = 2.0f - __builtin_amdgcn_sqrtf(sq);
        float e   = __expf(d);
        rsum[s] += e;  csum += e;
        if (d > rmax[s]) ridx[s] = col;        // cols ascend over jt -> first max
        rmax[s] = fmaxf(rmax[s], d);
        if (d > cmax) cs8 = s;                 // rows ascend with s -> first max
        cmax = fmaxf(cmax, d);
      }
    }

    // ---- col partial -> LDS atomics (DS pipe) ----
    int crow = ro + ((cs8 >> 2) << 4) + (cs8 & 3);
    unsigned long long ckey =
        ((unsigned long long)f2key(cmax) << 32) | (unsigned long long)(unsigned)(~(unsigned)crow);
    atomicMax(&lkey[jt * 16 + l15], ckey);
    atomicAdd(&lsum[jt * 16 + l15], csum);
  }

  // ---- row reduce: one butterfly over the 16 lane-columns ----
  unsigned long long rkk[8];
  #pragma unroll
  for (int s = 0; s < 8; ++s)
    rkk[s] = ((unsigned long long)f2key(rmax[s]) << 32) |
             (unsigned long long)(unsigned)(~(unsigned)ridx[s]);
  #pragma unroll
  for (int off = 1; off < 16; off <<= 1) {
    #pragma unroll
    for (int s = 0; s < 8; ++s) {
      rsum[s] += __shfl_xor(rsum[s], off);
      unsigned long long o = __shfl_xor(rkk[s], off);
      if (o > rkk[s]) rkk[s] = o;
    }
  }
  if (l15 == 0) {
    #pragma unroll
    for (int s = 0; s < 8; ++s) {
      int row = ro + ((s >> 2) << 4) + (s & 3);
      atomicMax(row_key + row, rkk[s]);
      atomicAdd(row_sum + row, rsum[s]);
    }
  }

  // ---- block-level col flush: 1 atomic pair per col ----
  __syncthreads();
  #pragma unroll
  for (int q = 0; q < 2; ++q) {
    int t = threadIdx.x + q * 256;
    atomicMax(col_key + colbase + t, lkey[t]);
    atomicAdd(col_sum + colbase + t, lsum[t]);
  }

  // ---- last block performs the finalize (device-scope handoff) ----
  __threadfence();
  if (threadIdx.x == 0)
    lastflag = (atomicAdd(done, 1u) == (16u * 64u - 1u)) ? 1u : 0u;
  __syncthreads();
  if (lastflag) {
    __threadfence();
    for (int j = threadIdx.x; j < MCOLS; j += 256) {
      unsigned long long ck =
          __hip_atomic_load(col_key + j, __ATOMIC_RELAXED, __HIP_MEMORY_SCOPE_AGENT);
      float csv =
          __hip_atomic_load(col_sum + j, __ATOMIC_RELAXED, __HIP_MEMORY_SCOPE_AGENT);
      int   ci   = (int)(~(unsigned)ck);
      float cmax = key2f((unsigned)(ck >> 32));
      float lp_col = cmax - logf(csv);

      unsigned long long rk =
          __hip_atomic_load(row_key + ci, __ATOMIC_RELAXED, __HIP_MEMORY_SCOPE_AGENT);
      float rsv =
          __hip_atomic_load(row_sum + ci, __ATOMIC_RELAXED, __HIP_MEMORY_SCOPE_AGENT);
      int   rj   = (int)(~(unsigned)rk);
      float rmx  = key2f((unsigned)(rk >> 32));
      float lp_row = rmx - logf(rsv);

      int mut = (rj == j);
      out[j]                 = mut ? (lp_row + lp_col) : 0.0f;
      out[MCOLS + 2 * j + 0] = (float)ci;
      out[MCOLS + 2 * j + 1] = (float)j;
      out[3 * MCOLS + j]     = mut ? 1.0f : 0.0f;
    }
  }
}

extern "C" void kernel_launch(void* const* d_in, const int* in_sizes, int n_in,
                              void* d_out, int out_size, void* d_ws, size_t ws_size,
                              hipStream_t stream) {
  const float* x = (const float*)d_in[0];
  const float* y = (const float*)d_in[1];
  float* out = (float*)d_out;

  char* ws = (char*)d_ws;
  unsigned long long* row_key = (unsigned long long*)(ws);            // 64 KB
  unsigned long long* col_key = (unsigned long long*)(ws + 65536);    // 64 KB
  float* row_sum = (float*)(ws + 131072);                             // 32 KB
  float* col_sum = (float*)(ws + 163840);                             // 32 KB
  float* xn      = (float*)(ws + 196608);                             // 32 KB
  float* yn      = (float*)(ws + 229376);                             // 32 KB
  _Float16* xh = (_Float16*)(ws + 262144);                            // 1 MB each
  _Float16* xl = (_Float16*)(ws + 262144 + 1048576);
  _Float16* yh = (_Float16*)(ws + 262144 + 2097152);
  _Float16* yl = (_Float16*)(ws + 262144 + 3145728);
  unsigned* done = (unsigned*)(ws + 262144 + 4194304);                // 4 B

  convert_kernel<<<512, 256, 0, stream>>>(x, y, xh, xl, yh, yl, xn, yn,
                                          row_key, col_key, row_sum, col_sum, done);
  dim3 grid(MCOLS / 512, NROWS / 128);     // 16 x 64 blocks, 256 threads
  mfma_tile_kernel<<<grid, 256, 0, stream>>>(xh, xl, yh, yl, xn, yn,
                                             row_key, row_sum, col_key, col_sum,
                                             done, out);
}

// Round 6
// 129.379 us; speedup vs baseline: 1.4625x; 1.4625x over previous
//
#include <hip/hip_runtime.h>
#include <stdint.h>

#define NROWS 8192
#define MCOLS 8192
#define DDIM  64

typedef _Float16 half8   __attribute__((ext_vector_type(8)));
typedef float    floatx4 __attribute__((ext_vector_type(4)));

// ---------- monotone float <-> uint key (for atomicMax argmax) ----------
__device__ __forceinline__ unsigned f2key(float f) {
  unsigned u = __float_as_uint(f);
  return (u & 0x80000000u) ? ~u : (u | 0x80000000u);
}
__device__ __forceinline__ float key2f(unsigned k) {
  unsigned u = (k & 0x80000000u) ? (k & 0x7fffffffu) : ~k;
  return __uint_as_float(u);
}

// ---------- fused: fp16-split conversion + row norms + accumulator init -------
// One thread per element, one wave per row (64 k-values). Coalesced 4B loads;
// 2B stores land in the row's 2KB fragment block (j-contiguous lanes combine).
// Fragment layout (16x16x32 f16 A/B operand): for (row,k):
//   halfpos = (row>>4)*1024 + (k>>5)*512 + (((k>>3)&3)*16 + (row&15))*8 + (k&7)
__global__ void convert_kernel(const float* __restrict__ x, const float* __restrict__ y,
                               _Float16* __restrict__ xh, _Float16* __restrict__ xl,
                               _Float16* __restrict__ yh, _Float16* __restrict__ yl,
                               float* __restrict__ xn, float* __restrict__ yn,
                               unsigned long long* __restrict__ rk,
                               unsigned long long* __restrict__ ck,
                               float* __restrict__ rs, float* __restrict__ cs) {
  const int gid  = blockIdx.x * 256 + threadIdx.x;   // 0 .. 1048575
  if (gid < NROWS) { rk[gid] = 0ull; rs[gid] = 0.0f; ck[gid] = 0ull; cs[gid] = 0.0f; }

  const int row  = gid >> 6;                          // 0 .. 16383
  const int k    = threadIdx.x & 63;                  // lane == k (wave-aligned)
  const float* src; _Float16 *dh, *dl; float* nout; int r;
  if (row < NROWS) { src = x; dh = xh; dl = xl; nout = xn; r = row; }
  else             { src = y; dh = yh; dl = yl; nout = yn; r = row - NROWS; }

  float f = src[(size_t)r * DDIM + k];
  _Float16 h = (_Float16)f;
  _Float16 l = (_Float16)((f - (float)h) * 2048.0f);
  int pos = ((r >> 4) << 10) + ((k >> 5) << 9) + ((((k >> 3) & 3) << 4) + (r & 15)) * 8 + (k & 7);
  dh[pos] = h;
  dl[pos] = l;

  float s = f * f;
  #pragma unroll
  for (int off = 32; off > 0; off >>= 1) s += __shfl_down(s, off);
  if (k == 0) nout[r] = s;
}

// ---------- main pass: block = 4 waves, each wave 32 rows x 256 cols ----------
__global__ __launch_bounds__(256, 4) void mfma_tile_kernel(
    const _Float16* __restrict__ xh, const _Float16* __restrict__ xl,
    const _Float16* __restrict__ yh, const _Float16* __restrict__ yl,
    const float* __restrict__ xn, const float* __restrict__ yn,
    unsigned long long* __restrict__ row_key, float* __restrict__ row_sum,
    unsigned long long* __restrict__ col_key, float* __restrict__ col_sum)
{
  __shared__ unsigned long long lkey[256];   // per-block col keys (2 KB)
  __shared__ float              lsum[256];   //                    (1 KB)

  const int wave = threadIdx.x >> 6;
  const int lane = threadIdx.x & 63;
  const int l15  = lane & 15;
  const int g    = lane >> 4;                // row-group 0..3
  const int ap0  = blockIdx.y * 8 + wave * 2;       // first of 2 A panels
  const int ro   = ap0 * 16 + g * 4;                // first row this lane covers
  const int colbase = blockIdx.x * 256;

  lkey[threadIdx.x] = 0ull;
  lsum[threadIdx.x] = 0.0f;
  __syncthreads();

  // ---- A fragments: 2 panels x (2 hi + 2 lo chunks), 32 VGPRs ----
  const half8* xh8 = (const half8*)xh;
  const half8* xl8 = (const half8*)xl;
  const half8* yh8 = (const half8*)yh;
  const half8* yl8 = (const half8*)yl;
  const size_t a0 = (size_t)ap0 * 128 + lane;
  half8 Ah[2][2], Al[2][2];
  #pragma unroll
  for (int p = 0; p < 2; ++p) {
    Ah[p][0] = xh8[a0 + p * 128];      Ah[p][1] = xh8[a0 + p * 128 + 64];
    Al[p][0] = xl8[a0 + p * 128];      Al[p][1] = xl8[a0 + p * 128 + 64];
  }

  // ---- per-row state: 8 rows/lane ----
  float xne[8], rsum[8], rmax[8]; int ridx[8];
  #pragma unroll
  for (int s = 0; s < 8; ++s) {
    xne[s]  = xn[ro + ((s >> 2) << 4) + (s & 3)];
    rsum[s] = 0.0f; rmax[s] = -3.4e38f; ridx[s] = 0;
  }

  // ---- jt loop over 16 col panels, B prefetched one panel ahead ----
  const size_t bbase = (size_t)(blockIdx.x * 16) * 128 + lane;
  half8 nbh0 = yh8[bbase], nbh1 = yh8[bbase + 64];
  half8 nbl0 = yl8[bbase], nbl1 = yl8[bbase + 64];

  for (int jt = 0; jt < 16; ++jt) {
    const half8 bh0 = nbh0, bh1 = nbh1, bl0 = nbl0, bl1 = nbl1;
    const int col = colbase + jt * 16 + l15;
    const float ync = yn[col];
    if (jt < 15) {
      const size_t nb = bbase + (size_t)(jt + 1) * 128;
      nbh0 = yh8[nb];  nbh1 = yh8[nb + 64];
      nbl0 = yl8[nb];  nbl1 = yl8[nb + 64];
    }

    float csum = 0.0f, cmax = -3.4e38f; int cs8 = 0;
    #pragma unroll
    for (int p = 0; p < 2; ++p) {
      floatx4 c1 = {}, c2 = {};
      c1 = __builtin_amdgcn_mfma_f32_16x16x32_f16(Ah[p][0], bh0, c1, 0, 0, 0);
      c1 = __builtin_amdgcn_mfma_f32_16x16x32_f16(Ah[p][1], bh1, c1, 0, 0, 0);
      c2 = __builtin_amdgcn_mfma_f32_16x16x32_f16(Al[p][0], bh0, c2, 0, 0, 0);
      c2 = __builtin_amdgcn_mfma_f32_16x16x32_f16(Al[p][1], bh1, c2, 0, 0, 0);
      c2 = __builtin_amdgcn_mfma_f32_16x16x32_f16(Ah[p][0], bl0, c2, 0, 0, 0);
      c2 = __builtin_amdgcn_mfma_f32_16x16x32_f16(Ah[p][1], bl1, c2, 0, 0, 0);
      #pragma unroll
      for (int r = 0; r < 4; ++r) {
        const int s = p * 4 + r;
        float dot = fmaf(c2[r], (1.0f / 2048.0f), c1[r]);
        float sq  = fmaxf(fmaf(-2.0f, dot, xne[s] + ync), 0.0f);
        float d   = 2.0f - __builtin_amdgcn_sqrtf(sq);
        float e   = __expf(d);
        rsum[s] += e;  csum += e;
        if (d > rmax[s]) ridx[s] = col;        // cols ascend over jt -> first max
        rmax[s] = fmaxf(rmax[s], d);
        if (d > cmax) cs8 = s;                 // rows ascend with s -> first max
        cmax = fmaxf(cmax, d);
      }
    }

    // ---- col partial -> LDS atomics (DS pipe) ----
    int crow = ro + ((cs8 >> 2) << 4) + (cs8 & 3);
    unsigned long long ckey =
        ((unsigned long long)f2key(cmax) << 32) | (unsigned long long)(unsigned)(~(unsigned)crow);
    atomicMax(&lkey[jt * 16 + l15], ckey);
    atomicAdd(&lsum[jt * 16 + l15], csum);
  }

  // ---- row reduce: one butterfly over the 16 lane-columns ----
  unsigned long long rkk[8];
  #pragma unroll
  for (int s = 0; s < 8; ++s)
    rkk[s] = ((unsigned long long)f2key(rmax[s]) << 32) |
             (unsigned long long)(unsigned)(~(unsigned)ridx[s]);
  #pragma unroll
  for (int off = 1; off < 16; off <<= 1) {
    #pragma unroll
    for (int s = 0; s < 8; ++s) {
      rsum[s] += __shfl_xor(rsum[s], off);
      unsigned long long o = __shfl_xor(rkk[s], off);
      if (o > rkk[s]) rkk[s] = o;
    }
  }
  if (l15 == 0) {
    #pragma unroll
    for (int s = 0; s < 8; ++s) {
      int row = ro + ((s >> 2) << 4) + (s & 3);
      atomicMax(row_key + row, rkk[s]);
      atomicAdd(row_sum + row, rsum[s]);
    }
  }

  // ---- block-level col flush: 1 atomic pair per col ----
  __syncthreads();
  {
    int col = colbase + threadIdx.x;
    atomicMax(col_key + col, lkey[threadIdx.x]);
    atomicAdd(col_sum + col, lsum[threadIdx.x]);
  }
}

// ---------- finalize: unpack keys, mutual test, write outputs ----------
__global__ void finalize_kernel(const unsigned long long* __restrict__ row_key,
                                const float* __restrict__ row_sum,
                                const unsigned long long* __restrict__ col_key,
                                const float* __restrict__ col_sum,
                                float* __restrict__ out)
{
  int j = blockIdx.x * 256 + threadIdx.x;
  if (j >= MCOLS) return;
  unsigned long long ck = col_key[j];
  int   ci   = (int)(~(unsigned)ck);
  float cmax = key2f((unsigned)(ck >> 32));
  float lp_col = cmax - logf(col_sum[j]);

  unsigned long long rk = row_key[ci];
  int   rj   = (int)(~(unsigned)rk);
  float rmax = key2f((unsigned)(rk >> 32));
  float lp_row = rmax - logf(row_sum[ci]);

  int mut = (rj == j);
  out[j]                 = mut ? (lp_row + lp_col) : 0.0f;
  out[MCOLS + 2 * j + 0] = (float)ci;
  out[MCOLS + 2 * j + 1] = (float)j;
  out[3 * MCOLS + j]     = mut ? 1.0f : 0.0f;
}

extern "C" void kernel_launch(void* const* d_in, const int* in_sizes, int n_in,
                              void* d_out, int out_size, void* d_ws, size_t ws_size,
                              hipStream_t stream) {
  const float* x = (const float*)d_in[0];
  const float* y = (const float*)d_in[1];
  float* out = (float*)d_out;

  char* ws = (char*)d_ws;
  unsigned long long* row_key = (unsigned long long*)(ws);            // 64 KB
  unsigned long long* col_key = (unsigned long long*)(ws + 65536);    // 64 KB
  float* row_sum = (float*)(ws + 131072);                             // 32 KB
  float* col_sum = (float*)(ws + 163840);                             // 32 KB
  float* xn      = (float*)(ws + 196608);                             // 32 KB
  float* yn      = (float*)(ws + 229376);                             // 32 KB
  _Float16* xh = (_Float16*)(ws + 262144);                            // 1 MB each
  _Float16* xl = (_Float16*)(ws + 262144 + 1048576);
  _Float16* yh = (_Float16*)(ws + 262144 + 2097152);
  _Float16* yl = (_Float16*)(ws + 262144 + 3145728);

  convert_kernel<<<4096, 256, 0, stream>>>(x, y, xh, xl, yh, yl, xn, yn,
                                           row_key, col_key, row_sum, col_sum);
  dim3 grid(MCOLS / 256, NROWS / 128);     // 32 x 64 blocks, 256 threads
  mfma_tile_kernel<<<grid, 256, 0, stream>>>(xh, xl, yh, yl, xn, yn,
                                             row_key, row_sum, col_key, col_sum);
  finalize_kernel<<<32, 256, 0, stream>>>(row_key, row_sum, col_key, col_sum, out);
}